// Round 2
// 360.388 us; speedup vs baseline: 1.0061x; 1.0061x over previous
//
#include <hip/hip_runtime.h>

// QuerySHLayerDeprecated: per-edge SH(lmax=2) + smooth radial basis embed.
// Inputs (float32 / int32 per reference):
//   d_in[0] = pos        f32[100000*3]
//   d_in[1] = query_pos  f32[10000*3]
//   d_in[2] = edge_src   int32[4000000]  (rows of query_pos)
//   d_in[3] = edge_dst   int32[4000000]  (rows of pos)
// Output d_out (float32): edge_sh[4M*9] then edge_embed[4M*10], flat concat.
//
// R4/R5: writeback was store-issue/VALU bound ([edge][19] LDS rows forced
// 38 scalar ds_reads + 38 scalar stores + div-by-9/10 address math per
// thread). Fix: LDS layout == output layout (sh[512*9], emb[512*10]
// contiguous) so writeback is an aligned LDS->global memcpy via
// ds_read_b128 + nontemporal global_store_dwordx4. R5 compile fix:
// __builtin_nontemporal_store needs a clang ext_vector type, not HIP's
// float4 class -> use floatx4 typedef for the memcpy path.

#define SQRT3F 1.7320508075688772f
// SMOOTH_C * sqrt(10) = 1.14136 * e^2 * sqrt(10)
#define EMB_K 26.6692997f
#define TPB 256
#define EPB 512                  // edges per block (2 per thread)
#define NSH4 (EPB * 9 / 4)       // 1152 float4s of SH per block
#define NEM4 (EPB * 10 / 4)      // 1280 float4s of embed per block

typedef float floatx4 __attribute__((ext_vector_type(4)));

__global__ __launch_bounds__(256) void pad_kernel(
    const float* __restrict__ pos, const float* __restrict__ qpos,
    float4* __restrict__ pos4, float4* __restrict__ qpos4,
    int npos, int nq)
{
    int i = blockIdx.x * blockDim.x + threadIdx.x;
    if (i < npos)
        pos4[i] = make_float4(pos[3 * i + 0], pos[3 * i + 1], pos[3 * i + 2], 0.f);
    if (i < nq)
        qpos4[i] = make_float4(qpos[3 * i + 0], qpos[3 * i + 1], qpos[3 * i + 2], 0.f);
}

// Compute one edge: 9 SH values into sh[0..8] (word-stride-9 LDS row,
// odd stride -> 2-way bank alias only, free), 10 embed values into em2
// (5 float2 zero writes + <=2 scalar overwrites in the active window).
__device__ __forceinline__ void compute_edge(
    float ax, float ay, float az, float bx, float by, float bz,
    float* __restrict__ sh, float2* __restrict__ em2)
{
    float vx = ax - bx, vy = ay - by, vz = az - bz;
    float r2 = vx * vx + vy * vy + vz * vz;
    float r = sqrtf(r2);
    float inv = (r > 0.f) ? (1.f / r) : 1.f;
    float x = vx * inv, y = vy * inv, z = vz * inv;

    sh[0] = 1.f;
    sh[1] = x;
    sh[2] = y;
    sh[3] = z;
    sh[4] = SQRT3F * x * z;
    sh[5] = SQRT3F * x * y;
    sh[6] = y * y - 0.5f * (x * x + z * z);
    sh[7] = SQRT3F * y * z;
    sh[8] = 0.5f * SQRT3F * (z * z - x * x);

    // zero-fill embed row (vector LDS writes), then set the window.
#pragma unroll
    for (int j = 0; j < 5; ++j) em2[j] = make_float2(0.f, 0.f);

    // embed: t = 11*r; basis j nonzero only for t in (j, j+2); windows
    // overlap by 1 => at most two nonzero, j in {floor(t)-1, floor(t)}.
    float t = r * 11.f;
    int k = (int)t;  // t >= 0, trunc == floor
    float* e = (float*)em2;
#pragma unroll
    for (int m = 0; m < 2; ++m) {
        int j = k - 1 + m;
        float a = t - (float)j;
        float b = (float)(j + 2) - t;
        if (j >= 0 && j < 10 && a > 0.f && b > 0.f)
            e[j] = EMB_K * __expf(-(__frcp_rn(a) + __frcp_rn(b)));
    }
}

template <bool PAD>
__global__ __launch_bounds__(256) void qsh_kernel(
    const float* __restrict__ pos,
    const float* __restrict__ qpos,
    const float4* __restrict__ pos4,
    const float4* __restrict__ qpos4,
    const int* __restrict__ esrc,
    const int* __restrict__ edst,
    float* __restrict__ out_sh,
    float* __restrict__ out_emb,
    int n)
{
    // LDS layout == output layout: contiguous [512*9] and [512*10].
    __shared__ __align__(16) float sh_lds[EPB * 9];
    __shared__ __align__(16) float emb_lds[EPB * 10];

    const int tid = threadIdx.x;
    const int base = blockIdx.x * EPB;
    const int count = min(EPB, n - base);

    if (count == EPB) {
#pragma unroll
        for (int m = 0; m < 2; ++m) {
            int le = tid + m * TPB;      // local edge id
            int e = base + le;
            // nontemporal: 32MB index streams must not thrash L1/L2
            int s = __builtin_nontemporal_load(esrc + e);
            int d = __builtin_nontemporal_load(edst + e);
            float ax, ay, az, bx, by, bz;
            if (PAD) {
                float4 q = qpos4[s];
                float4 p = pos4[d];
                ax = q.x; ay = q.y; az = q.z;
                bx = p.x; by = p.y; bz = p.z;
            } else {
                ax = qpos[3 * s + 0]; ay = qpos[3 * s + 1]; az = qpos[3 * s + 2];
                bx = pos[3 * d + 0];  by = pos[3 * d + 1];  bz = pos[3 * d + 2];
            }
            compute_edge(ax, ay, az, bx, by, bz,
                         sh_lds + le * 9, (float2*)(emb_lds + le * 10));
        }
    } else {
#pragma unroll
        for (int m = 0; m < 2; ++m) {
            int le = tid + m * TPB;
            if (le < count) {
                int e = base + le;
                int s = __builtin_nontemporal_load(esrc + e);
                int d = __builtin_nontemporal_load(edst + e);
                float ax, ay, az, bx, by, bz;
                if (PAD) {
                    float4 q = qpos4[s];
                    float4 p = pos4[d];
                    ax = q.x; ay = q.y; az = q.z;
                    bx = p.x; by = p.y; bz = p.z;
                } else {
                    ax = qpos[3 * s + 0]; ay = qpos[3 * s + 1]; az = qpos[3 * s + 2];
                    bx = pos[3 * d + 0];  by = pos[3 * d + 1];  bz = pos[3 * d + 2];
                }
                compute_edge(ax, ay, az, bx, by, bz,
                             sh_lds + le * 9, (float2*)(emb_lds + le * 10));
            }
        }
    }
    __syncthreads();

    // Pure memcpy writeback: ds_read_b128 + nontemporal global_store_dwordx4.
    // Block base offsets: base*9 and base*10 words are both /4 -> 16B aligned.
    floatx4* osh4 = (floatx4*)(out_sh + (size_t)base * 9);
    floatx4* oem4 = (floatx4*)(out_emb + (size_t)base * 10);
    const floatx4* shv = (const floatx4*)sh_lds;
    const floatx4* emv = (const floatx4*)emb_lds;

    if (count == EPB) {
#pragma unroll
        for (int k = 0; k < 5; ++k) {          // 1152 = 4.5*256
            int i4 = k * TPB + tid;
            if (i4 < NSH4)
                __builtin_nontemporal_store(shv[i4], osh4 + i4);
        }
#pragma unroll
        for (int k = 0; k < 5; ++k) {          // 1280 = 5*256 exactly
            int i4 = k * TPB + tid;
            __builtin_nontemporal_store(emv[i4], oem4 + i4);
        }
    } else {
        float* osh = out_sh + (size_t)base * 9;
        float* oem = out_emb + (size_t)base * 10;
        int nsh = count * 9;
        for (int idx = tid; idx < nsh; idx += TPB)
            __builtin_nontemporal_store(sh_lds[idx], osh + idx);
        int nem = count * 10;
        for (int idx = tid; idx < nem; idx += TPB)
            __builtin_nontemporal_store(emb_lds[idx], oem + idx);
    }
}

extern "C" void kernel_launch(void* const* d_in, const int* in_sizes, int n_in,
                              void* d_out, int out_size, void* d_ws, size_t ws_size,
                              hipStream_t stream) {
    const float* pos  = (const float*)d_in[0];
    const float* qpos = (const float*)d_in[1];
    const int* esrc = (const int*)d_in[2];
    const int* edst = (const int*)d_in[3];
    int npos = in_sizes[0] / 3;   // 100000
    int nq   = in_sizes[1] / 3;   // 10000
    int n    = in_sizes[2];       // 4,000,000 edges

    float* out_sh  = (float*)d_out;
    float* out_emb = out_sh + (size_t)n * 9;

    int grid = (n + EPB - 1) / EPB;

    size_t need = ((size_t)npos + (size_t)nq) * sizeof(float4);
    if (ws_size >= need) {
        float4* pos4  = (float4*)d_ws;
        float4* qpos4 = pos4 + npos;
        int pgrid = (max(npos, nq) + TPB - 1) / TPB;
        pad_kernel<<<pgrid, TPB, 0, stream>>>(pos, qpos, pos4, qpos4, npos, nq);
        qsh_kernel<true><<<grid, TPB, 0, stream>>>(
            pos, qpos, pos4, qpos4, esrc, edst, out_sh, out_emb, n);
    } else {
        qsh_kernel<false><<<grid, TPB, 0, stream>>>(
            pos, qpos, nullptr, nullptr, esrc, edst, out_sh, out_emb, n);
    }
}